// Round 4
// baseline (246.471 us; speedup 1.0000x reference)
//
#include <hip/hip_runtime.h>

// PhysicsConstrainedLoss: 6 loss terms over 6.4M edges / 200K nodes.
// R3: p1 keeps everything needed for the scatter in LDS (packed entries built
// in sub-pass 1), eliminating the 51MB global re-read; 2048-edge blocks for
// occupancy (21KB LDS -> 7 blocks/CU); fused sigmoid/softplus (one expf);
// rsqrt for the current denominator. Scatter stays: one range-reservation
// global atomic per (block,bucket), int20-quantized deterministic sums.

constexpr int   kNodes         = 200000;
constexpr int   kEdges         = 6400000;
constexpr int   kNumSums       = 9;
constexpr float kEps           = 1e-6f;

constexpr int   kBucketShift   = 12;                 // 4096 nodes / bucket
constexpr int   kBucketSize    = 1 << kBucketShift;
constexpr int   kBuckets       = (kNodes + kBucketSize - 1) / kBucketSize;  // 49
constexpr int   kCap           = 272 * 1024;         // per-bucket capacity
constexpr int   kEdgesPerBlk   = 2048;
constexpr int   kP1Blocks      = kEdges / kEdgesPerBlk;   // 3125
static_assert(kEdges % kEdgesPerBlk == 0, "exact tiling assumed");
constexpr int   kEntriesPerBlk = 2 * kEdgesPerBlk;   // 4096
constexpr int   kMSlices       = 16;
constexpr int   kP2Blocks      = kBuckets * kMSlices; // 784
constexpr int   kNodeBlocks    = 256;
constexpr int   kFbBlocks      = 2048;
constexpr float kQScale        = 65536.0f;
constexpr float kQInv          = 1.0f / 65536.0f;
constexpr int   kQBias         = 524288;             // int20 bias

__device__ __forceinline__ float softplusf(float t) {
    return fmaxf(t, 0.0f) + log1pf(expf(-fabsf(t)));
}

// ---------------------------------------------------------------- phase 1
__global__ __launch_bounds__(256) void p1_edges(
    const float* __restrict__ nf,
    const float* __restrict__ logits,
    const float* __restrict__ eparams,
    const float* __restrict__ labels,
    const float* __restrict__ tparams,
    const int*   __restrict__ srcs,
    const int*   __restrict__ dsts,
    unsigned*    __restrict__ pairs,    // (kBuckets, kCap)
    int*         __restrict__ gcount,   // (kBuckets,) zeroed
    float*       __restrict__ partials) // (kP1Blocks, kNumSums)
{
    __shared__ unsigned      ent[kEntriesPerBlk];     // 16 KB packed entries
    __shared__ unsigned char bkt[kEntriesPerBlk];     // 4 KB bucket ids
    __shared__ int   hist[kBuckets];
    __shared__ int   base[kBuckets];
    __shared__ int   cursor[kBuckets];
    __shared__ float smem[4][kNumSums];

    const int tid = threadIdx.x;
    for (int b = tid; b < kBuckets; b += 256) { hist[b] = 0; cursor[b] = 0; }
    __syncthreads();

    float acc[kNumSums];
#pragma unroll
    for (int k = 0; k < kNumSums; ++k) acc[k] = 0.0f;

    const int e0 = blockIdx.x * kEdgesPerBlk;

    // ---- sub-pass 1: full compute; entries + bucket ids into LDS; histogram
#pragma unroll 1
    for (int i = 0; i < kEdgesPerBlk / 256; ++i) {
        const int el = i * 256 + tid;
        const int e  = e0 + el;

        float  x  = logits[e];
        float  y  = labels[e];
        float2 ep = *reinterpret_cast<const float2*>(eparams + 2 * e);
        float2 tp = *reinterpret_cast<const float2*>(tparams + 2 * e);
        int    s  = srcs[e];
        int    d  = dsts[e];
        float2 vs = *reinterpret_cast<const float2*>(nf + 4 * s);
        float2 vd = *reinterpret_cast<const float2*>(nf + 4 * d);

        // fused sigmoid + BCE: t = exp(-|x|) shared
        float t      = expf(-fabsf(x));
        float inv1pt = 1.0f / (1.0f + t);
        float p      = (x >= 0.0f) ? inv1pt : t * inv1pt;
        float sp_nx  = fmaxf(-x, 0.0f) + log1pf(t);   // softplus(-x)
        float bce    = sp_nx + (1.0f - y) * x;        // y*sp(-x)+(1-y)*sp(x)

        float dr  = ep.x - tp.x;
        float dxx = ep.y - tp.y;
        float par = dr * dr + dxx * dxx;

        float dvr = vs.x - vd.x;
        float dvi = vs.y - vd.y;
        float mag = sqrtf(dvr * dvr + dvi * dvi);

        float Rp    = ep.x + kEps;
        float curp  = mag * rsqrtf(Rp * Rp + ep.y * ep.y) * p;
        float vdrop = mag * p;

        acc[0] += bce;
        acc[1] += par;
        acc[2] += p;
        acc[3] += p * ep.x;
        acc[4] += p * ep.y;
        acc[5] += p * ep.x * ep.x;
        acc[6] += p * ep.y * ep.y;
        acc[7] += vdrop;
        acc[8] += vdrop * vdrop;

        int q = __float2int_rn(curp * kQScale);
        q = max(-(kQBias - 1), min(kQBias - 1, q));

        const int bd = d >> kBucketShift;
        const int bs = s >> kBucketShift;
        atomicAdd(&hist[bd], 1);
        atomicAdd(&hist[bs], 1);

        ent[2 * el]     = ((unsigned)(d & (kBucketSize - 1)) << 20) | (unsigned)( q + kQBias);
        ent[2 * el + 1] = ((unsigned)(s & (kBucketSize - 1)) << 20) | (unsigned)(-q + kQBias);
        bkt[2 * el]     = (unsigned char)bd;
        bkt[2 * el + 1] = (unsigned char)bs;
    }
    __syncthreads();

    // ---- reserve contiguous global ranges: ONE global atomic per (block,bucket)
    for (int b = tid; b < kBuckets; b += 256)
        base[b] = atomicAdd(&gcount[b], hist[b]);
    __syncthreads();

    // ---- sub-pass 2: LDS-only scatter to global pair lists
#pragma unroll 1
    for (int j = tid; j < kEntriesPerBlk; j += 256) {
        const unsigned u = ent[j];
        const int b      = bkt[j];
        const int slot   = base[b] + atomicAdd(&cursor[b], 1);
        if (slot < kCap)
            pairs[(size_t)b * kCap + slot] = u;
    }

    // ---- block reduction of the 9 scalar sums
    const int lane = tid & 63;
    const int wave = tid >> 6;
#pragma unroll
    for (int k = 0; k < kNumSums; ++k) {
        float v = acc[k];
#pragma unroll
        for (int off = 32; off > 0; off >>= 1) v += __shfl_down(v, off, 64);
        if (lane == 0) smem[wave][k] = v;
    }
    __syncthreads();
    if (tid < kNumSums) {
        float v = 0.0f;
#pragma unroll
        for (int w = 0; w < 4; ++w) v += smem[w][tid];
        partials[blockIdx.x * kNumSums + tid] = v;
    }
}

// ---------------------------------------------------------------- phase 2
__global__ __launch_bounds__(256) void p2_buckets(
    const unsigned* __restrict__ pairs,
    const int*      __restrict__ gcount,
    int*            __restrict__ out_i32)  // (kP2Blocks, kBucketSize)
{
    __shared__ int accs[kBucketSize];
    const int b = blockIdx.x / kMSlices;
    const int m = blockIdx.x % kMSlices;

    for (int i = threadIdx.x; i < kBucketSize; i += 256) accs[i] = 0;
    __syncthreads();

    const int count = min(gcount[b], kCap);
    const int s0 = (int)((long long)count * m / kMSlices);
    const int s1 = (int)((long long)count * (m + 1) / kMSlices);
    const unsigned* pb = pairs + (size_t)b * kCap;

    for (int i = s0 + threadIdx.x; i < s1; i += 256) {
        const unsigned u = pb[i];
        atomicAdd(&accs[u >> 20], (int)(u & 0xFFFFFu) - kQBias);
    }
    __syncthreads();

    int* o = out_i32 + (size_t)blockIdx.x * kBucketSize;
    for (int i = threadIdx.x; i < kBucketSize; i += 256) o[i] = accs[i];
}

// ---------------------------------------------------------------- node pass
__global__ __launch_bounds__(256) void node_pass_binned(
    const int* __restrict__ out_i32,
    float*     __restrict__ node_partials)
{
    float acc = 0.0f;
    const int stride = gridDim.x * blockDim.x;
    for (int n = blockIdx.x * blockDim.x + threadIdx.x; n < kNodes; n += stride) {
        const int b = n >> kBucketShift;
        const int s = n & (kBucketSize - 1);
        const int* p = out_i32 + ((size_t)b * kMSlices) * kBucketSize + s;
        int v = 0;
#pragma unroll
        for (int m = 0; m < kMSlices; ++m) v += p[(size_t)m * kBucketSize];
        const float nc = (float)v * kQInv;
        acc += nc * nc;
    }
    __shared__ float smem[4];
    const int lane = threadIdx.x & 63;
    const int wave = threadIdx.x >> 6;
    float v = acc;
#pragma unroll
    for (int off = 32; off > 0; off >>= 1) v += __shfl_down(v, off, 64);
    if (lane == 0) smem[wave] = v;
    __syncthreads();
    if (threadIdx.x == 0)
        node_partials[blockIdx.x] = smem[0] + smem[1] + smem[2] + smem[3];
}

// ---------------------------------------------------------------- fallback (atomic path)
__global__ __launch_bounds__(256) void edge_pass_atomic(
    const float* __restrict__ nf, const float* __restrict__ logits,
    const float* __restrict__ eparams, const float* __restrict__ labels,
    const float* __restrict__ tparams, const int* __restrict__ srcs,
    const int* __restrict__ dsts, float* __restrict__ node_cur,
    float* __restrict__ partials)
{
    float acc[kNumSums];
#pragma unroll
    for (int k = 0; k < kNumSums; ++k) acc[k] = 0.0f;
    const int stride = gridDim.x * blockDim.x;
    for (int e = blockIdx.x * blockDim.x + threadIdx.x; e < kEdges; e += stride) {
        float  x  = logits[e];
        float  y  = labels[e];
        float2 ep = *reinterpret_cast<const float2*>(eparams + 2 * e);
        float2 tp = *reinterpret_cast<const float2*>(tparams + 2 * e);
        int    s  = srcs[e];
        int    d  = dsts[e];
        float2 vs = *reinterpret_cast<const float2*>(nf + 4 * s);
        float2 vd = *reinterpret_cast<const float2*>(nf + 4 * d);
        float p   = 1.0f / (1.0f + expf(-x));
        float bce = y * softplusf(-x) + (1.0f - y) * softplusf(x);
        float dr = ep.x - tp.x, dxx = ep.y - tp.y;
        float dvr = vs.x - vd.x, dvi = vs.y - vd.y;
        float mag = sqrtf(dvr * dvr + dvi * dvi);
        float Rp  = ep.x + kEps;
        float den = sqrtf(Rp * Rp + ep.y * ep.y);
        float curp = (mag / den) * p;
        float vdrop = mag * p;
        acc[0] += bce; acc[1] += dr * dr + dxx * dxx; acc[2] += p;
        acc[3] += p * ep.x; acc[4] += p * ep.y;
        acc[5] += p * ep.x * ep.x; acc[6] += p * ep.y * ep.y;
        acc[7] += vdrop; acc[8] += vdrop * vdrop;
        atomicAdd(node_cur + d,  curp);
        atomicAdd(node_cur + s, -curp);
    }
    __shared__ float smem[4][kNumSums];
    const int lane = threadIdx.x & 63, wave = threadIdx.x >> 6;
#pragma unroll
    for (int k = 0; k < kNumSums; ++k) {
        float v = acc[k];
#pragma unroll
        for (int off = 32; off > 0; off >>= 1) v += __shfl_down(v, off, 64);
        if (lane == 0) smem[wave][k] = v;
    }
    __syncthreads();
    if (threadIdx.x < kNumSums) {
        float v = 0.0f;
#pragma unroll
        for (int w = 0; w < 4; ++w) v += smem[w][threadIdx.x];
        partials[blockIdx.x * kNumSums + threadIdx.x] = v;
    }
}

__global__ __launch_bounds__(256) void node_pass_flat(
    const float* __restrict__ node_cur, float* __restrict__ node_partials)
{
    float acc = 0.0f;
    const int stride = gridDim.x * blockDim.x;
    for (int i = blockIdx.x * blockDim.x + threadIdx.x; i < kNodes; i += stride) {
        float v = node_cur[i];
        acc += v * v;
    }
    __shared__ float smem[4];
    const int lane = threadIdx.x & 63, wave = threadIdx.x >> 6;
    float v = acc;
#pragma unroll
    for (int off = 32; off > 0; off >>= 1) v += __shfl_down(v, off, 64);
    if (lane == 0) smem[wave] = v;
    __syncthreads();
    if (threadIdx.x == 0)
        node_partials[blockIdx.x] = smem[0] + smem[1] + smem[2] + smem[3];
}

// ---------------------------------------------------------------- finalize
__global__ __launch_bounds__(64) void finalize(
    const float* __restrict__ partials, int nblocks,
    const float* __restrict__ node_partials,
    float*       __restrict__ out)
{
    const int lane = threadIdx.x;
    double sums[kNumSums];
#pragma unroll
    for (int k = 0; k < kNumSums; ++k) {
        double s = 0.0;
        for (int i = lane; i < nblocks; i += 64)
            s += (double)partials[i * kNumSums + k];
#pragma unroll
        for (int off = 32; off > 0; off >>= 1) s += __shfl_down(s, off, 64);
        sums[k] = s;
    }
    double nsum = 0.0;
    for (int i = lane; i < kNodeBlocks; i += 64)
        nsum += (double)node_partials[i];
#pragma unroll
    for (int off = 32; off > 0; off >>= 1) nsum += __shfl_down(nsum, off, 64);

    if (lane == 0) {
        const double E = (double)kEdges, N = (double)kNodes;
        const double s_bce = sums[0], s_par = sums[1], s_p = sums[2];
        const double s_pR = sums[3], s_pX = sums[4];
        const double s_pR2 = sums[5], s_pX2 = sums[6];
        const double s_v = sums[7], s_v2 = sums[8];

        double topology  = s_bce / E;
        double parameter = s_par / (2.0 * E);
        double kcl       = 0.1 * (nsum / N);

        double denom = s_p + (double)kEps;
        double mR = s_pR / denom, mX = s_pX / denom;
        double varR = s_pR2 - 2.0 * mR * s_pR + mR * mR * s_p;
        double varX = s_pX2 - 2.0 * mX * s_pX + mX * mX * s_p;
        double param_consistency = 0.5 * (varR + varX);
        double voltage_consistency = (s_v2 - (s_v * s_v) / E) / (E - 1.0);
        double kvl = 0.1 * (param_consistency + voltage_consistency);

        double ecl = s_p - (N - 1.0);
        ecl = ecl * ecl;
        double radial   = 0.1 * (ecl + 0.1 * (s_p / E));
        double sparsity = 0.01 * (s_p / E);
        double total = topology + parameter + kcl + kvl + radial + sparsity;

        out[0] = (float)topology;  out[1] = (float)parameter;
        out[2] = (float)kcl;       out[3] = (float)kvl;
        out[4] = (float)radial;    out[5] = (float)sparsity;
        out[6] = (float)total;
    }
}

extern "C" void kernel_launch(void* const* d_in, const int* in_sizes, int n_in,
                              void* d_out, int out_size, void* d_ws, size_t ws_size,
                              hipStream_t stream) {
    const float* nf      = (const float*)d_in[0];
    const float* logits  = (const float*)d_in[1];
    const float* eparams = (const float*)d_in[2];
    const float* labels  = (const float*)d_in[3];
    const float* tparams = (const float*)d_in[4];
    const int*   eidx    = (const int*)d_in[5];
    float* out           = (float*)d_out;

    // binned layout: [pairs][out_i32][gcount(pad 64)][partials][node_partials]
    const size_t n_pairs  = (size_t)kBuckets * kCap;
    const size_t n_outi32 = (size_t)kP2Blocks * kBucketSize;
    const size_t n_words  = n_pairs + n_outi32 + 64 +
                            (size_t)kP1Blocks * kNumSums + kNodeBlocks;

    if (ws_size >= n_words * sizeof(unsigned)) {
        unsigned* pairs         = (unsigned*)d_ws;
        int*      out_i32       = (int*)(pairs + n_pairs);
        int*      gcount        = (int*)(out_i32 + n_outi32);
        float*    partials      = (float*)(gcount + 64);
        float*    node_partials = partials + (size_t)kP1Blocks * kNumSums;

        hipMemsetAsync(gcount, 0, kBuckets * sizeof(int), stream);
        p1_edges<<<kP1Blocks, 256, 0, stream>>>(nf, logits, eparams, labels, tparams,
                                                eidx, eidx + kEdges,
                                                pairs, gcount, partials);
        p2_buckets<<<kP2Blocks, 256, 0, stream>>>(pairs, gcount, out_i32);
        node_pass_binned<<<kNodeBlocks, 256, 0, stream>>>(out_i32, node_partials);
        finalize<<<1, 64, 0, stream>>>(partials, kP1Blocks, node_partials, out);
    } else {
        float* node_cur      = (float*)d_ws;
        float* partials      = node_cur + kNodes;
        float* node_partials = partials + (size_t)kFbBlocks * kNumSums;

        hipMemsetAsync(node_cur, 0, kNodes * sizeof(float), stream);
        edge_pass_atomic<<<kFbBlocks, 256, 0, stream>>>(nf, logits, eparams, labels,
                                                        tparams, eidx, eidx + kEdges,
                                                        node_cur, partials);
        node_pass_flat<<<kNodeBlocks, 256, 0, stream>>>(node_cur, node_partials);
        finalize<<<1, 64, 0, stream>>>(partials, kFbBlocks, node_partials, out);
    }
}

// Round 5
// 185.585 us; speedup vs baseline: 1.3281x; 1.3281x over previous
//
#include <hip/hip_runtime.h>

// PhysicsConstrainedLoss: 6 loss terms over 6.4M edges / 200K nodes.
// R4: the scatter's global writes were 12.8M 4B stores at data-dependent
// addresses (~49 buckets live per wave-store => ~64 TCC transactions per
// wave). Now each block counting-sorts its 4096 entries by bucket in LDS
// (entries held in REGISTERS across the histogram barrier), then copies out
// bucket-contiguous runs => coalesced streaming stores. One global
// range-reservation atomic per (block,bucket). Deterministic int20 sums.

constexpr int   kNodes         = 200000;
constexpr int   kEdges         = 6400000;
constexpr int   kNumSums       = 9;
constexpr float kEps           = 1e-6f;

constexpr int   kBucketShift   = 12;                 // 4096 nodes / bucket
constexpr int   kBucketSize    = 1 << kBucketShift;
constexpr int   kBuckets       = (kNodes + kBucketSize - 1) / kBucketSize;  // 49
constexpr int   kCap           = 272 * 1024;         // per-bucket capacity
constexpr int   kEdgesPerBlk   = 2048;
constexpr int   kEdgesPerThr   = kEdgesPerBlk / 256; // 8
constexpr int   kEntPerThr     = 2 * kEdgesPerThr;   // 16
constexpr int   kP1Blocks      = kEdges / kEdgesPerBlk;   // 3125
static_assert(kEdges % kEdgesPerBlk == 0, "exact tiling assumed");
constexpr int   kEntriesPerBlk = 2 * kEdgesPerBlk;   // 4096
constexpr int   kMSlices       = 32;
constexpr int   kP2Blocks      = kBuckets * kMSlices; // 1568
constexpr int   kNodeBlocks    = 256;
constexpr int   kFbBlocks      = 2048;
constexpr float kQScale        = 65536.0f;
constexpr float kQInv          = 1.0f / 65536.0f;
constexpr int   kQBias         = 524288;             // int20 bias

__device__ __forceinline__ float softplusf(float t) {
    return fmaxf(t, 0.0f) + log1pf(expf(-fabsf(t)));
}

// ---------------------------------------------------------------- phase 1
__global__ __launch_bounds__(256) void p1_edges(
    const float* __restrict__ nf,
    const float* __restrict__ logits,
    const float* __restrict__ eparams,
    const float* __restrict__ labels,
    const float* __restrict__ tparams,
    const int*   __restrict__ srcs,
    const int*   __restrict__ dsts,
    unsigned*    __restrict__ pairs,    // (kBuckets, kCap)
    int*         __restrict__ gcount,   // (kBuckets,) zeroed
    float*       __restrict__ partials) // (kP1Blocks, kNumSums)
{
    __shared__ unsigned      sorted[kEntriesPerBlk];  // 16 KB bucket-sorted entries
    __shared__ unsigned char sbkt[kEntriesPerBlk];    // 4 KB bucket id per slot
    __shared__ int   hist[kBuckets];
    __shared__ int   offs[kBuckets];
    __shared__ int   base[kBuckets];
    __shared__ int   cursor[kBuckets];
    __shared__ float smem[4][kNumSums];

    const int tid = threadIdx.x;
    for (int b = tid; b < kBuckets; b += 256) hist[b] = 0;
    __syncthreads();

    float acc[kNumSums];
#pragma unroll
    for (int k = 0; k < kNumSums; ++k) acc[k] = 0.0f;

    unsigned uent[kEntPerThr];   // registers (loop fully unrolled, static idx)
    unsigned ubkt[kEntPerThr];

    const int e0 = blockIdx.x * kEdgesPerBlk;

    // ---- pass A: compute everything; entries stay in registers; histogram
#pragma unroll
    for (int i = 0; i < kEdgesPerThr; ++i) {
        const int e = e0 + i * 256 + tid;

        float  x  = logits[e];
        float  y  = labels[e];
        float2 ep = *reinterpret_cast<const float2*>(eparams + 2 * e);
        float2 tp = *reinterpret_cast<const float2*>(tparams + 2 * e);
        int    s  = srcs[e];
        int    d  = dsts[e];
        float2 vs = *reinterpret_cast<const float2*>(nf + 4 * s);
        float2 vd = *reinterpret_cast<const float2*>(nf + 4 * d);

        // fused sigmoid + BCE: t = exp(-|x|) shared
        float t      = expf(-fabsf(x));
        float inv1pt = 1.0f / (1.0f + t);
        float p      = (x >= 0.0f) ? inv1pt : t * inv1pt;
        float sp_nx  = fmaxf(-x, 0.0f) + log1pf(t);   // softplus(-x)
        float bce    = sp_nx + (1.0f - y) * x;

        float dr  = ep.x - tp.x;
        float dxx = ep.y - tp.y;

        float dvr = vs.x - vd.x;
        float dvi = vs.y - vd.y;
        float mag = sqrtf(dvr * dvr + dvi * dvi);

        float Rp    = ep.x + kEps;
        float curp  = mag * rsqrtf(Rp * Rp + ep.y * ep.y) * p;
        float vdrop = mag * p;

        acc[0] += bce;
        acc[1] += dr * dr + dxx * dxx;
        acc[2] += p;
        acc[3] += p * ep.x;
        acc[4] += p * ep.y;
        acc[5] += p * ep.x * ep.x;
        acc[6] += p * ep.y * ep.y;
        acc[7] += vdrop;
        acc[8] += vdrop * vdrop;

        int q = __float2int_rn(curp * kQScale);
        q = max(-(kQBias - 1), min(kQBias - 1, q));

        const int bd = d >> kBucketShift;
        const int bs = s >> kBucketShift;
        atomicAdd(&hist[bd], 1);
        atomicAdd(&hist[bs], 1);

        uent[2 * i]     = ((unsigned)(d & (kBucketSize - 1)) << 20) | (unsigned)( q + kQBias);
        uent[2 * i + 1] = ((unsigned)(s & (kBucketSize - 1)) << 20) | (unsigned)(-q + kQBias);
        ubkt[2 * i]     = (unsigned)bd;
        ubkt[2 * i + 1] = (unsigned)bs;
    }
    __syncthreads();

    // ---- wave 0: prefix-scan hist, reserve global ranges, reset cursors
    if (tid < 64) {
        const int lane = tid;
        int h    = (lane < kBuckets) ? hist[lane] : 0;
        int incl = h;
#pragma unroll
        for (int o = 1; o < 64; o <<= 1) {
            int n = __shfl_up(incl, o, 64);
            if (lane >= o) incl += n;
        }
        if (lane < kBuckets) {
            offs[lane]   = incl - h;
            cursor[lane] = 0;
            base[lane]   = atomicAdd(&gcount[lane], h);
        }
    }
    __syncthreads();

    // ---- pass B: scatter registers -> bucket-sorted LDS
#pragma unroll
    for (int k = 0; k < kEntPerThr; ++k) {
        const int b   = (int)ubkt[k];
        const int pos = offs[b] + atomicAdd(&cursor[b], 1);
        sorted[pos] = uent[k];
        sbkt[pos]   = (unsigned char)b;
    }
    __syncthreads();

    // ---- pass C: coalesced copy-out (consecutive slots -> consecutive addrs)
#pragma unroll 1
    for (int j = tid; j < kEntriesPerBlk; j += 256) {
        const int b   = (int)sbkt[j];
        const int dst = base[b] + (j - offs[b]);
        if (dst < kCap)
            pairs[(size_t)b * kCap + dst] = sorted[j];
    }

    // ---- block reduction of the 9 scalar sums
    const int lane = tid & 63;
    const int wave = tid >> 6;
#pragma unroll
    for (int k = 0; k < kNumSums; ++k) {
        float v = acc[k];
#pragma unroll
        for (int off = 32; off > 0; off >>= 1) v += __shfl_down(v, off, 64);
        if (lane == 0) smem[wave][k] = v;
    }
    __syncthreads();
    if (tid < kNumSums) {
        float v = 0.0f;
#pragma unroll
        for (int w = 0; w < 4; ++w) v += smem[w][tid];
        partials[blockIdx.x * kNumSums + tid] = v;
    }
}

// ---------------------------------------------------------------- phase 2
__global__ __launch_bounds__(256) void p2_buckets(
    const unsigned* __restrict__ pairs,
    const int*      __restrict__ gcount,
    int*            __restrict__ out_i32)  // (kP2Blocks, kBucketSize)
{
    __shared__ int accs[kBucketSize];
    const int b = blockIdx.x / kMSlices;
    const int m = blockIdx.x % kMSlices;

    for (int i = threadIdx.x; i < kBucketSize; i += 256) accs[i] = 0;
    __syncthreads();

    const int count = min(gcount[b], kCap);
    const int s0 = (int)((long long)count * m / kMSlices);
    const int s1 = (int)((long long)count * (m + 1) / kMSlices);
    const unsigned* pb = pairs + (size_t)b * kCap;

    for (int i = s0 + threadIdx.x; i < s1; i += 256) {
        const unsigned u = pb[i];
        atomicAdd(&accs[u >> 20], (int)(u & 0xFFFFFu) - kQBias);
    }
    __syncthreads();

    int* o = out_i32 + (size_t)blockIdx.x * kBucketSize;
    for (int i = threadIdx.x; i < kBucketSize; i += 256) o[i] = accs[i];
}

// ---------------------------------------------------------------- node pass
__global__ __launch_bounds__(256) void node_pass_binned(
    const int* __restrict__ out_i32,
    float*     __restrict__ node_partials)
{
    float acc = 0.0f;
    const int stride = gridDim.x * blockDim.x;
    for (int n = blockIdx.x * blockDim.x + threadIdx.x; n < kNodes; n += stride) {
        const int b = n >> kBucketShift;
        const int s = n & (kBucketSize - 1);
        const int* p = out_i32 + ((size_t)b * kMSlices) * kBucketSize + s;
        int v = 0;
#pragma unroll
        for (int m = 0; m < kMSlices; ++m) v += p[(size_t)m * kBucketSize];
        const float nc = (float)v * kQInv;
        acc += nc * nc;
    }
    __shared__ float smem[4];
    const int lane = threadIdx.x & 63;
    const int wave = threadIdx.x >> 6;
    float v = acc;
#pragma unroll
    for (int off = 32; off > 0; off >>= 1) v += __shfl_down(v, off, 64);
    if (lane == 0) smem[wave] = v;
    __syncthreads();
    if (threadIdx.x == 0)
        node_partials[blockIdx.x] = smem[0] + smem[1] + smem[2] + smem[3];
}

// ---------------------------------------------------------------- fallback (atomic path)
__global__ __launch_bounds__(256) void edge_pass_atomic(
    const float* __restrict__ nf, const float* __restrict__ logits,
    const float* __restrict__ eparams, const float* __restrict__ labels,
    const float* __restrict__ tparams, const int* __restrict__ srcs,
    const int* __restrict__ dsts, float* __restrict__ node_cur,
    float* __restrict__ partials)
{
    float acc[kNumSums];
#pragma unroll
    for (int k = 0; k < kNumSums; ++k) acc[k] = 0.0f;
    const int stride = gridDim.x * blockDim.x;
    for (int e = blockIdx.x * blockDim.x + threadIdx.x; e < kEdges; e += stride) {
        float  x  = logits[e];
        float  y  = labels[e];
        float2 ep = *reinterpret_cast<const float2*>(eparams + 2 * e);
        float2 tp = *reinterpret_cast<const float2*>(tparams + 2 * e);
        int    s  = srcs[e];
        int    d  = dsts[e];
        float2 vs = *reinterpret_cast<const float2*>(nf + 4 * s);
        float2 vd = *reinterpret_cast<const float2*>(nf + 4 * d);
        float p   = 1.0f / (1.0f + expf(-x));
        float bce = y * softplusf(-x) + (1.0f - y) * softplusf(x);
        float dr = ep.x - tp.x, dxx = ep.y - tp.y;
        float dvr = vs.x - vd.x, dvi = vs.y - vd.y;
        float mag = sqrtf(dvr * dvr + dvi * dvi);
        float Rp  = ep.x + kEps;
        float den = sqrtf(Rp * Rp + ep.y * ep.y);
        float curp = (mag / den) * p;
        float vdrop = mag * p;
        acc[0] += bce; acc[1] += dr * dr + dxx * dxx; acc[2] += p;
        acc[3] += p * ep.x; acc[4] += p * ep.y;
        acc[5] += p * ep.x * ep.x; acc[6] += p * ep.y * ep.y;
        acc[7] += vdrop; acc[8] += vdrop * vdrop;
        atomicAdd(node_cur + d,  curp);
        atomicAdd(node_cur + s, -curp);
    }
    __shared__ float smem[4][kNumSums];
    const int lane = threadIdx.x & 63, wave = threadIdx.x >> 6;
#pragma unroll
    for (int k = 0; k < kNumSums; ++k) {
        float v = acc[k];
#pragma unroll
        for (int off = 32; off > 0; off >>= 1) v += __shfl_down(v, off, 64);
        if (lane == 0) smem[wave][k] = v;
    }
    __syncthreads();
    if (threadIdx.x < kNumSums) {
        float v = 0.0f;
#pragma unroll
        for (int w = 0; w < 4; ++w) v += smem[w][threadIdx.x];
        partials[blockIdx.x * kNumSums + threadIdx.x] = v;
    }
}

__global__ __launch_bounds__(256) void node_pass_flat(
    const float* __restrict__ node_cur, float* __restrict__ node_partials)
{
    float acc = 0.0f;
    const int stride = gridDim.x * blockDim.x;
    for (int i = blockIdx.x * blockDim.x + threadIdx.x; i < kNodes; i += stride) {
        float v = node_cur[i];
        acc += v * v;
    }
    __shared__ float smem[4];
    const int lane = threadIdx.x & 63, wave = threadIdx.x >> 6;
    float v = acc;
#pragma unroll
    for (int off = 32; off > 0; off >>= 1) v += __shfl_down(v, off, 64);
    if (lane == 0) smem[wave] = v;
    __syncthreads();
    if (threadIdx.x == 0)
        node_partials[blockIdx.x] = smem[0] + smem[1] + smem[2] + smem[3];
}

// ---------------------------------------------------------------- finalize
__global__ __launch_bounds__(256) void finalize(
    const float* __restrict__ partials, int nblocks,
    const float* __restrict__ node_partials, int nnp,
    float*       __restrict__ out)
{
    const int tid  = threadIdx.x;
    const int lane = tid & 63;
    const int wave = tid >> 6;
    __shared__ double red[4][kNumSums + 1];

    double s[kNumSums];
#pragma unroll
    for (int k = 0; k < kNumSums; ++k) s[k] = 0.0;
    for (int i = tid; i < nblocks; i += 256) {
#pragma unroll
        for (int k = 0; k < kNumSums; ++k)
            s[k] += (double)partials[i * kNumSums + k];
    }
    double ns = 0.0;
    for (int i = tid; i < nnp; i += 256) ns += (double)node_partials[i];

#pragma unroll
    for (int k = 0; k < kNumSums + 1; ++k) {
        double v = (k < kNumSums) ? s[k] : ns;
#pragma unroll
        for (int off = 32; off > 0; off >>= 1) v += __shfl_down(v, off, 64);
        if (lane == 0) red[wave][k] = v;
    }
    __syncthreads();

    if (tid == 0) {
        double sums[kNumSums + 1];
#pragma unroll
        for (int k = 0; k < kNumSums + 1; ++k)
            sums[k] = red[0][k] + red[1][k] + red[2][k] + red[3][k];

        const double E = (double)kEdges, N = (double)kNodes;
        const double s_bce = sums[0], s_par = sums[1], s_p = sums[2];
        const double s_pR = sums[3], s_pX = sums[4];
        const double s_pR2 = sums[5], s_pX2 = sums[6];
        const double s_v = sums[7], s_v2 = sums[8];
        const double nsum = sums[9];

        double topology  = s_bce / E;
        double parameter = s_par / (2.0 * E);
        double kcl       = 0.1 * (nsum / N);

        double denom = s_p + (double)kEps;
        double mR = s_pR / denom, mX = s_pX / denom;
        double varR = s_pR2 - 2.0 * mR * s_pR + mR * mR * s_p;
        double varX = s_pX2 - 2.0 * mX * s_pX + mX * mX * s_p;
        double param_consistency = 0.5 * (varR + varX);
        double voltage_consistency = (s_v2 - (s_v * s_v) / E) / (E - 1.0);
        double kvl = 0.1 * (param_consistency + voltage_consistency);

        double ecl = s_p - (N - 1.0);
        ecl = ecl * ecl;
        double radial   = 0.1 * (ecl + 0.1 * (s_p / E));
        double sparsity = 0.01 * (s_p / E);
        double total = topology + parameter + kcl + kvl + radial + sparsity;

        out[0] = (float)topology;  out[1] = (float)parameter;
        out[2] = (float)kcl;       out[3] = (float)kvl;
        out[4] = (float)radial;    out[5] = (float)sparsity;
        out[6] = (float)total;
    }
}

extern "C" void kernel_launch(void* const* d_in, const int* in_sizes, int n_in,
                              void* d_out, int out_size, void* d_ws, size_t ws_size,
                              hipStream_t stream) {
    const float* nf      = (const float*)d_in[0];
    const float* logits  = (const float*)d_in[1];
    const float* eparams = (const float*)d_in[2];
    const float* labels  = (const float*)d_in[3];
    const float* tparams = (const float*)d_in[4];
    const int*   eidx    = (const int*)d_in[5];
    float* out           = (float*)d_out;

    // binned layout: [pairs][out_i32][gcount(pad 64)][partials][node_partials]
    const size_t n_pairs  = (size_t)kBuckets * kCap;
    const size_t n_outi32 = (size_t)kP2Blocks * kBucketSize;
    const size_t n_words  = n_pairs + n_outi32 + 64 +
                            (size_t)kP1Blocks * kNumSums + kNodeBlocks;

    if (ws_size >= n_words * sizeof(unsigned)) {
        unsigned* pairs         = (unsigned*)d_ws;
        int*      out_i32       = (int*)(pairs + n_pairs);
        int*      gcount        = (int*)(out_i32 + n_outi32);
        float*    partials      = (float*)(gcount + 64);
        float*    node_partials = partials + (size_t)kP1Blocks * kNumSums;

        hipMemsetAsync(gcount, 0, kBuckets * sizeof(int), stream);
        p1_edges<<<kP1Blocks, 256, 0, stream>>>(nf, logits, eparams, labels, tparams,
                                                eidx, eidx + kEdges,
                                                pairs, gcount, partials);
        p2_buckets<<<kP2Blocks, 256, 0, stream>>>(pairs, gcount, out_i32);
        node_pass_binned<<<kNodeBlocks, 256, 0, stream>>>(out_i32, node_partials);
        finalize<<<1, 256, 0, stream>>>(partials, kP1Blocks, node_partials,
                                        kNodeBlocks, out);
    } else {
        float* node_cur      = (float*)d_ws;
        float* partials      = node_cur + kNodes;
        float* node_partials = partials + (size_t)kFbBlocks * kNumSums;

        hipMemsetAsync(node_cur, 0, kNodes * sizeof(float), stream);
        edge_pass_atomic<<<kFbBlocks, 256, 0, stream>>>(nf, logits, eparams, labels,
                                                        tparams, eidx, eidx + kEdges,
                                                        node_cur, partials);
        node_pass_flat<<<kNodeBlocks, 256, 0, stream>>>(node_cur, node_partials);
        finalize<<<1, 256, 0, stream>>>(partials, kFbBlocks, node_partials,
                                        kNodeBlocks, out);
    }
}